// Round 6
// baseline (271.326 us; speedup 1.0000x reference)
//
#include <hip/hip_runtime.h>

#define S_TOT 16384
#define DD 15
#define CC 64
#define WW 16
#define L2E  1.4426950408889634f
#define L2E2 2.8853900817779268f

typedef __attribute__((ext_vector_type(8))) short short8v;
typedef __attribute__((ext_vector_type(4))) float f32x4;

__device__ __forceinline__ float rcp_(float x){ return __builtin_amdgcn_rcpf(x); }
__device__ __forceinline__ float ex2_(float x){
#if __has_builtin(__builtin_amdgcn_exp2f)
  return __builtin_amdgcn_exp2f(x);
#else
  return exp2f(x);
#endif
}
__device__ __forceinline__ unsigned short f2bfu(float f){
  unsigned u = __float_as_uint(f);
  return (unsigned short)((u + 0x7FFFu + ((u>>16)&1u)) >> 16);
}
__device__ __forceinline__ float bfu2f(unsigned short s){
  return __uint_as_float(((unsigned)s)<<16);
}

// ============ prep: 47 blocks x 256 ============
// blocks 0..14: M2 row i (cols 0..14 = Wf2@Wf1, col 15 = Wf2@bf1+bf2) -> ws2[i*16+c]
// blocks 15..46: W_ih -> bf16 A-frag image (128KB) in wsW.
//   pair p = ((w*64+ct)*32 + l32); gate n = ct*16 + c16; q=(c16>>2), g=c16&3;
//   row = g*1024 + q*256 + w*64 + ct; k = (l32>>4)*8 + e; k==15 -> bias.
__global__ void __launch_bounds__(256)
prep_k(const float* __restrict__ W_ih, const float* __restrict__ b_ih,
       const float* __restrict__ b_hh, const float* __restrict__ Wf1,
       const float* __restrict__ bf1, const float* __restrict__ Wf2,
       const float* __restrict__ bf2,
       unsigned short* __restrict__ wsW, float* __restrict__ ws2) {
  const int tid = threadIdx.x, blk = blockIdx.x;
  if (blk < 15) {
    __shared__ float red[4][16];
    const int i = blk;
    float acc[16];
#pragma unroll
    for (int c = 0; c < 16; ++c) acc[c] = 0.f;
    for (int k = tid; k < 4096; k += 256) {
      const float w2 = Wf2[i*4096 + k];
      const float* f1 = Wf1 + k*15;
#pragma unroll
      for (int c = 0; c < 15; ++c) acc[c] = fmaf(w2, f1[c], acc[c]);
      acc[15] = fmaf(w2, bf1[k], acc[15]);
    }
#pragma unroll
    for (int c = 0; c < 16; ++c) {
#pragma unroll
      for (int off = 32; off; off >>= 1) acc[c] += __shfl_xor(acc[c], off);
    }
    if ((tid & 63) == 0) {
#pragma unroll
      for (int c = 0; c < 16; ++c) red[tid>>6][c] = acc[c];
    }
    __syncthreads();
    if (tid < 16) {
      float s = red[0][tid] + red[1][tid] + red[2][tid] + red[3][tid];
      if (tid == 15) s += bf2[i];
      ws2[i*16 + tid] = s;
    }
  } else {
    const int p = (blk - 15)*256 + tid;   // 0..8191
    const int l32 = p & 31, tt = p >> 5;
    const int ct = tt & 63, w = tt >> 6;
    const int hk = l32 >> 4, c16 = l32 & 15;
    const int q = c16 >> 2, g = c16 & 3;
    const int row = g*1024 + q*256 + w*64 + ct;
    const float sc = (g == 2) ? L2E2 : L2E;
    union { unsigned short us[8]; uint4 v; } u;
#pragma unroll
    for (int e = 0; e < 8; ++e) {
      const int k = hk*8 + e;
      const float val = (k < 15) ? W_ih[row*15 + k]*sc : (b_ih[row] + b_hh[row])*sc;
      u.us[e] = f2bfu(val);
    }
    *(uint4*)(wsW + p*8) = u.v;
  }
}

// ============ scan: 256 blocks x 256 threads (4 waves, 4 units/thread) ============
// LDS (dynamic):
#define OFF_BUF  0        // 4 waves x 16 cols x 2048B (XOR-swizzled 16B chunks) = 131072
#define OFF_XST  131072   // 80 rows x 16 ushort (k15 = 1.0) = 2560
#define OFF_FST  133632   // 64 rows x 16 ushort (k15 = 1.0) = 2048
#define OFF_M2   135680   // 15 x 16 floats (col15 = cf) = 960
#define OFF_SLOT 136640   // 2 x 4 floats
#define OFF_P2   136672   // 2 x 4 waves x 8 floats = 256
#define SMEM_TOT 136928

#define CELLQ(da, db, Q, HV, CV, CNEW, PACC) {                         \
  float pi_ = __uint_as_float((da) << 16);                             \
  float pf_ = __uint_as_float((da) & 0xFFFF0000u);                     \
  float pg_ = __uint_as_float((db) << 16);                             \
  float po_ = __uint_as_float((db) & 0xFFFF0000u);                     \
  float ai_ = fmaf(whhq[Q].x, (HV), pi_);                              \
  float af_ = fmaf(whhq[Q].y, (HV), pf_);                              \
  float ag_ = fmaf(whhq[Q].z, (HV), pg_);                              \
  float ao_ = fmaf(whhq[Q].w, (HV), po_);                              \
  float si_ = rcp_(1.f + ex2_(-ai_));                                  \
  float sf_ = rcp_(1.f + ex2_(-af_));                                  \
  float tg_ = fmaf(-2.f, rcp_(1.f + ex2_(ag_)), 1.f);                  \
  float so_ = rcp_(1.f + ex2_(-ao_));                                  \
  CNEW = fmaf(sf_, (CV), si_*tg_);                                     \
  float tc_ = fmaf(-2.f, rcp_(1.f + ex2_((CNEW)*L2E2)), 1.f);          \
  PACC = fmaf(wrq[Q], so_*tc_, PACC); }

extern "C" __global__ void __launch_bounds__(256, 1)
lstm_scan_k(const float* __restrict__ x, const float* __restrict__ W_hh,
            const float* __restrict__ W_hr,
            const unsigned short* __restrict__ wsW, const float* __restrict__ ws2,
            float* __restrict__ out) {
  extern __shared__ char smem[];
  unsigned short* xst = (unsigned short*)(smem + OFF_XST);
  unsigned short* fst = (unsigned short*)(smem + OFF_FST);
  float* m2f  = (float*)(smem + OFF_M2);
  float* slotf= (float*)(smem + OFF_SLOT);
  float* p2f  = (float*)(smem + OFF_P2);

  const int tid = threadIdx.x;
  const int l = tid & 63, w = tid >> 6;
  const int l4 = l >> 4, r16 = l & 15;
  const int blk = blockIdx.x;
  const int t0 = blk * CC;
  char* wbase = smem + OFF_BUF + w*32768;

  // ---- phase A ----
  for (int idx = tid; idx < 1280; idx += 256) {
    const int r = idx >> 4, k = idx & 15;
    const int t = t0 - WW + r;
    const float v = (k == 15) ? 1.f : ((t >= 0) ? x[t*DD + k] : 0.f);
    xst[idx] = f2bfu(v);
  }
  if (tid < 240) m2f[tid] = ws2[tid];
  __syncthreads();
#pragma unroll
  for (int it = 0; it < 4; ++it) {
    const int idx = tid + it*256;
    if (idx < 960) {
      const int tf = idx/15, i = idx - tf*15;
      float acc = m2f[i*16 + 15];
#pragma unroll
      for (int m = 0; m < DD; ++m) acc = fmaf(m2f[i*16+m], bfu2f(xst[(WW+tf)*16 + m]), acc);
      out[2*S_TOT + (t0 + tf)*DD + i] = acc;
      fst[tf*16 + i] = f2bfu(acc);
    }
  }
  if (tid < 64) fst[tid*16 + 15] = 0x3F80;

  // per-thread recurrent params (unit q*256 + tid)
  float4 whhq[4]; float wrq[4];
#pragma unroll
  for (int q = 0; q < 4; ++q) {
    const int u = q*256 + tid;
    whhq[q] = make_float4(W_hh[u]*L2E, W_hh[1024+u]*L2E, W_hh[2048+u]*L2E2, W_hh[3072+u]*L2E);
    wrq[q] = W_hr[u];
  }
  __syncthreads();

  // ---- window GEMM: A = W-frags (stream from wsW), B = x/f cols; C[gate][step] -> swizzled LDS
  auto stage_window = [&](short8v bfrag) {
#pragma unroll 8
    for (int ct = 0; ct < 64; ++ct) {
      short8v a = (short8v)0;
      if (l < 32) a = *(const short8v*)((const char*)wsW + (((w*64 + ct)*32 + l) << 4));
      f32x4 z = {0.f, 0.f, 0.f, 0.f};
      f32x4 d = __builtin_amdgcn_mfma_f32_16x16x32_bf16(a, bfrag, z, 0, 0, 0);
      const unsigned u0 = ((unsigned)f2bfu(d[1]) << 16) | f2bfu(d[0]);
      const unsigned u1 = ((unsigned)f2bfu(d[3]) << 16) | f2bfu(d[2]);
      const int ci = ((l4 >> 1) << 6) | ct;
      *(uint2*)(wbase + r16*2048 + ((ci ^ r16) << 4) + ((l4 & 1) << 3)) = make_uint2(u0, u1);
    }
  };
  auto read_gates = [&](int cn, uint4& ga, uint4& gb) {
    const char* base = wbase + cn*2048;
    ga = *(const uint4*)(base + ((l ^ cn) << 4));
    gb = *(const uint4*)(base + (((64 + l) ^ cn) << 4));
  };

  float h = 0.f;
  float cst[4] = {0.f, 0.f, 0.f, 0.f};
  int buf = 0;

  // ---- warm window: 16 steps from xst rows 0..15 ----
  {
    short8v b = (short8v)0;
    if (l < 32) b = *(const short8v*)((char*)xst + r16*32 + l4*16);
    stage_window(b);
    const float lv = (blk == 0) ? 0.f : 1.f;
    for (int s = 0; s < WW; ++s) {
      uint4 ga, gb;
      read_gates(s, ga, gb);
      float p1 = 0.f;
      float cn0, cn1, cn2, cn3;
      CELLQ(ga.x, ga.y, 0, h, cst[0], cn0, p1);
      CELLQ(ga.z, ga.w, 1, h, cst[1], cn1, p1);
      CELLQ(gb.x, gb.y, 2, h, cst[2], cn2, p1);
      CELLQ(gb.z, gb.w, 3, h, cst[3], cn3, p1);
      cst[0] = lv*cn0; cst[1] = lv*cn1; cst[2] = lv*cn2; cst[3] = lv*cn3;
      p1 *= lv;
#pragma unroll
      for (int off = 32; off; off >>= 1) p1 += __shfl_xor(p1, off);
      if (l == 0) slotf[buf*4 + w] = p1;
      __syncthreads();
      const float4 sv = *(const float4*)(slotf + buf*4);
      h = sv.x + sv.y + sv.z + sv.w;
      buf ^= 1;
    }
  }

  // ---- main: 8 windows x 8 steps; cell2 batched per window, published one window late
  float hh[8], chh0[8], chh1[8], chh2[8], chh3[8];
  for (int m = 0; m < 8; ++m) {
    {
      short8v b = (short8v)0;
      if (l < 32) {
        const char* rb = (r16 < 8) ? ((char*)xst + (WW + 8*m + r16)*32)
                                   : ((char*)fst + (8*m + r16 - 8)*32);
        b = *(const short8v*)(rb + l4*16);
      }
      stage_window(b);
    }
#pragma unroll
    for (int r = 0; r < 8; ++r) {
      uint4 ga, gb;
      read_gates(r, ga, gb);
      float p1 = 0.f;
      float cn0, cn1, cn2, cn3;
      CELLQ(ga.x, ga.y, 0, h, cst[0], cn0, p1);
      CELLQ(ga.z, ga.w, 1, h, cst[1], cn1, p1);
      CELLQ(gb.x, gb.y, 2, h, cst[2], cn2, p1);
      CELLQ(gb.z, gb.w, 3, h, cst[3], cn3, p1);
      cst[0] = cn0; cst[1] = cn1; cst[2] = cn2; cst[3] = cn3;
      chh0[r] = cn0; chh1[r] = cn1; chh2[r] = cn2; chh3[r] = cn3;
#pragma unroll
      for (int off = 32; off; off >>= 1) p1 += __shfl_xor(p1, off);
      if (l == 0) slotf[buf*4 + w] = p1;
      __syncthreads();
      if (r == 0 && m > 0 && tid < 8) {
        const float* pp = p2f + ((m-1) & 1)*32;
        out[S_TOT + t0 + 8*(m-1) + tid] = pp[tid] + pp[8+tid] + pp[16+tid] + pp[24+tid];
      }
      const float4 sv = *(const float4*)(slotf + buf*4);
      h = sv.x + sv.y + sv.z + sv.w;
      hh[r] = h;
      if (tid == 0) out[t0 + 8*m + r] = h;
      buf ^= 1;
    }
    // cell2 batch (uses h1,c1 of each step; state not updated)
    float p2r[8];
#pragma unroll
    for (int r = 0; r < 8; ++r) {
      uint4 ga, gb;
      read_gates(8 + r, ga, gb);
      float p2 = 0.f, dum;
      CELLQ(ga.x, ga.y, 0, hh[r], chh0[r], dum, p2);
      CELLQ(ga.z, ga.w, 1, hh[r], chh1[r], dum, p2);
      CELLQ(gb.x, gb.y, 2, hh[r], chh2[r], dum, p2);
      CELLQ(gb.z, gb.w, 3, hh[r], chh3[r], dum, p2);
      p2r[r] = p2;
    }
#pragma unroll
    for (int r = 0; r < 8; ++r) {
#pragma unroll
      for (int off = 32; off; off >>= 1) p2r[r] += __shfl_xor(p2r[r], off);
    }
    if (l == 0) {
#pragma unroll
      for (int r = 0; r < 8; ++r) p2f[(m & 1)*32 + w*8 + r] = p2r[r];
    }
  }
  __syncthreads();
  if (tid < 8) {
    const float* pp = p2f + 32;  // (7 & 1) = 1
    out[S_TOT + t0 + 56 + tid] = pp[tid] + pp[8+tid] + pp[16+tid] + pp[24+tid];
  }
}

extern "C" void kernel_launch(void* const* d_in, const int* in_sizes, int n_in,
                              void* d_out, int out_size, void* d_ws, size_t ws_size,
                              hipStream_t stream) {
  const float* x    = (const float*)d_in[0];
  const float* W_ih = (const float*)d_in[1];
  const float* W_hh = (const float*)d_in[2];
  const float* b_ih = (const float*)d_in[3];
  const float* b_hh = (const float*)d_in[4];
  const float* W_hr = (const float*)d_in[5];
  const float* Wf1  = (const float*)d_in[6];
  const float* bf1  = (const float*)d_in[7];
  const float* Wf2  = (const float*)d_in[8];
  const float* bf2  = (const float*)d_in[9];
  float* out = (float*)d_out;
  unsigned short* wsW = (unsigned short*)d_ws;
  float* ws2 = (float*)((char*)d_ws + 131072);

  hipLaunchKernelGGL(prep_k, dim3(47), dim3(256), 0, stream,
                     W_ih, b_ih, b_hh, Wf1, bf1, Wf2, bf2, wsW, ws2);
  (void)hipFuncSetAttribute((const void*)lstm_scan_k,
                            hipFuncAttributeMaxDynamicSharedMemorySize, SMEM_TOT);
  hipLaunchKernelGGL(lstm_scan_k, dim3(256), dim3(256), SMEM_TOT, stream,
                     x, W_hh, W_hr, wsW, ws2, out);
}

// Round 8
// 197.165 us; speedup vs baseline: 1.3761x; 1.3761x over previous
//
#include <hip/hip_runtime.h>

#define S_TOT 16384
#define DD 15
#define L2E  1.4426950408889634f
#define L2E2 2.8853900817779268f

typedef __attribute__((ext_vector_type(8))) short short8v;
typedef __attribute__((ext_vector_type(4))) float f32x4;

__device__ __forceinline__ float rcp_(float x){ return __builtin_amdgcn_rcpf(x); }
__device__ __forceinline__ float ex2_(float x){
#if __has_builtin(__builtin_amdgcn_exp2f)
  return __builtin_amdgcn_exp2f(x);
#else
  return exp2f(x);
#endif
}
__device__ __forceinline__ unsigned short f2bfu(float f){
  unsigned u = __float_as_uint(f);
  return (unsigned short)((u + 0x7FFFu + ((u>>16)&1u)) >> 16);
}
__device__ __forceinline__ float bfu2f(unsigned short s){
  return __uint_as_float(((unsigned)s)<<16);
}

// ============ prep: 47 blocks x 256 ============
// blocks 0..14: M2 row i -> ws2[i*16+c] (c<15: Wf2@Wf1; c==15: Wf2@bf1+bf2)
// blocks 15..46: W_ih -> bf16 B-frag image (round-4 mapping):
//   pair p = (w*16+ct)*32 + l32; c16=l32&15, hk=l32>>4; n=ct*16+c16;
//   g=n&3, ul=n>>2; row = g*1024 + w*64 + ul; k=hk*8+e (k==15 -> bias).
__global__ void __launch_bounds__(256)
prep_k(const float* __restrict__ W_ih, const float* __restrict__ b_ih,
       const float* __restrict__ b_hh, const float* __restrict__ Wf1,
       const float* __restrict__ bf1, const float* __restrict__ Wf2,
       const float* __restrict__ bf2,
       unsigned short* __restrict__ wsW, float* __restrict__ ws2) {
  const int tid = threadIdx.x, blk = blockIdx.x;
  if (blk < 15) {
    __shared__ float red[4][16];
    const int i = blk;
    float acc[16];
#pragma unroll
    for (int c = 0; c < 16; ++c) acc[c] = 0.f;
    for (int k = tid; k < 4096; k += 256) {
      const float w2 = Wf2[i*4096 + k];
      const float* f1 = Wf1 + k*15;
#pragma unroll
      for (int c = 0; c < 15; ++c) acc[c] = fmaf(w2, f1[c], acc[c]);
      acc[15] = fmaf(w2, bf1[k], acc[15]);
    }
#pragma unroll
    for (int c = 0; c < 16; ++c) {
#pragma unroll
      for (int off = 32; off; off >>= 1) acc[c] += __shfl_xor(acc[c], off);
    }
    if ((tid & 63) == 0) {
#pragma unroll
      for (int c = 0; c < 16; ++c) red[tid>>6][c] = acc[c];
    }
    __syncthreads();
    if (tid < 16) {
      float s = red[0][tid] + red[1][tid] + red[2][tid] + red[3][tid];
      if (tid == 15) s += bf2[i];
      ws2[i*16 + tid] = s;
    }
  } else {
    const int p = (blk - 15)*256 + tid;   // 0..8191
    const int l32 = p & 31, tt = p >> 5;
    const int ct = tt & 15, w = tt >> 4;
    const int hk = l32 >> 4, c16 = l32 & 15;
    const int n = ct*16 + c16, g = n & 3, ul = n >> 2;
    const int row = g*1024 + w*64 + ul;
    const float sc = (g == 2) ? L2E2 : L2E;
    union { unsigned short us[8]; uint4 v; } u;
#pragma unroll
    for (int e = 0; e < 8; ++e) {
      const int k = hk*8 + e;
      const float val = (k < 15) ? W_ih[row*15 + k]*sc : (b_ih[row] + b_hh[row])*sc;
      u.us[e] = f2bfu(val);
    }
    *(uint4*)(wsW + p*8) = u.v;
  }
}

// ============ scan: 256 blocks x 1024 threads, 2 chunks/block ============
// LDS layout (bytes):
#define OFF_PRE  0        // 16 waves x (16 rows x 264 ushort = 528B) = 135168
#define PW_STR   8448
#define OFF_XST  135168   // 80 rows x 16 ushort (k15 = 1.0) = 2560
#define OFF_FST  137728   // 64 rows x 16 ushort (k15 = 1.0) = 2048
#define OFF_M2   139776   // 15x16 floats (col15 = cf) = 960
#define OFF_SLOT 140736   // float2[2][16] = 256
#define OFF_P2   140992   // float2[2][16 waves][4] = 1024
#define SMEM_TOT 142016

#define CELL(G, HV, CV, CNEW, PV) {                              \
  float pi_ = __uint_as_float((G).x << 16);                      \
  float pf_ = __uint_as_float((G).x & 0xFFFF0000u);              \
  float pg_ = __uint_as_float((G).y << 16);                      \
  float po_ = __uint_as_float((G).y & 0xFFFF0000u);              \
  float ai_ = fmaf(whhx, (HV), pi_);                             \
  float af_ = fmaf(whhy, (HV), pf_);                             \
  float ag_ = fmaf(whhz, (HV), pg_);                             \
  float ao_ = fmaf(whhw, (HV), po_);                             \
  float si_ = rcp_(1.f + ex2_(-ai_));                            \
  float sf_ = rcp_(1.f + ex2_(-af_));                            \
  float tg_ = fmaf(-2.f, rcp_(1.f + ex2_(ag_)), 1.f);            \
  float so_ = rcp_(1.f + ex2_(-ao_));                            \
  CNEW = fmaf(sf_, (CV), si_*tg_);                               \
  float tc_ = fmaf(-2.f, rcp_(1.f + ex2_((CNEW)*L2E2)), 1.f);    \
  PV = wr*(so_*tc_); }

extern "C" __global__ void __launch_bounds__(1024, 2)
lstm_scan_k(const float* __restrict__ x, const float* __restrict__ W_hh,
            const float* __restrict__ W_hr,
            const unsigned short* __restrict__ wsW, const float* __restrict__ ws2,
            float* __restrict__ out) {
  extern __shared__ char smem[];
  unsigned short* xst = (unsigned short*)(smem + OFF_XST);
  unsigned short* fst = (unsigned short*)(smem + OFF_FST);
  float*  m2f  = (float*)(smem + OFF_M2);
  float2* slot = (float2*)(smem + OFF_SLOT);
  float2* p2f  = (float2*)(smem + OFF_P2);

  const int j = threadIdx.x;
  const int l = j & 63, w = j >> 6;
  const int r16 = l & 15, hk = l >> 4;
  const int blk = blockIdx.x;
  const int tA = blk * 64, tB = tA + 32;
  char* myPre = smem + OFF_PRE + w*PW_STR;

  // ---- phase A: stage x rows (t0-16 .. t0+63), M2, forecasts ----
  for (int idx = j; idx < 80*16; idx += 1024) {
    const int r = idx >> 4, k = idx & 15;
    const int t = tA - 16 + r;
    const float v = (k == 15) ? 1.f : ((t >= 0) ? x[t*DD + k] : 0.f);
    xst[idx] = f2bfu(v);
  }
  if (j < 240) m2f[j] = ws2[j];
  __syncthreads();
  if (j < 960) {
    const int tf = j/15, i = j - tf*15;
    float acc = m2f[i*16 + 15];
#pragma unroll
    for (int m = 0; m < DD; ++m) acc = fmaf(m2f[i*16+m], bfu2f(xst[(16+tf)*16 + m]), acc);
    out[2*S_TOT + (tA + tf)*DD + i] = acc;
    fst[tf*16 + i] = f2bfu(acc);
  } else {
    fst[(j - 960)*16 + 15] = 0x3F80;  // bias slot = 1.0
  }

  const float whhx = W_hh[j]*L2E, whhy = W_hh[1024+j]*L2E,
              whhz = W_hh[2048+j]*L2E2, whhw = W_hh[3072+j]*L2E;
  const float wr = W_hr[j];
  __syncthreads();

  // ---- per-wave window GEMM: A = 16 step-rows, B = wave's 256 gate-cols ----
  auto stage_window = [&](const unsigned short* rp) {
    short8v a = (short8v)0;
    if (l < 32) a = *(const short8v*)((const char*)rp + hk*16);
#pragma unroll
    for (int ct = 0; ct < 16; ++ct) {
      short8v bb = (short8v)0;
      if (l < 32) bb = ((const short8v*)wsW)[(w*16 + ct)*32 + l];
      f32x4 z = {0.f, 0.f, 0.f, 0.f};
      f32x4 d = __builtin_amdgcn_mfma_f32_16x16x32_bf16(a, bb, z, 0, 0, 0);
      char* cb = myPre + (ct*16 + r16)*2;
#pragma unroll
      for (int r2 = 0; r2 < 4; ++r2)
        *(unsigned short*)(cb + (4*hk + r2)*528) = f2bfu(d[r2]);
    }
  };

  float hA = 0.f, hB = 0.f, cA = 0.f, cB = 0.f;
  int buf = 0;
  const float lvA = (blk == 0) ? 0.f : 1.f;

  // ---- warm: 2 windows x 8 step-pairs (cell1 only; A masked on block 0) ----
  for (int ww2 = 0; ww2 < 2; ++ww2) {
    const unsigned short* rp = (r16 < 8) ? (xst + (8*ww2 + r16)*16)
                                         : (xst + (32 + 8*ww2 + (r16 - 8))*16);
    stage_window(rp);
    for (int r = 0; r < 8; ++r) {
      const uint2 gA = *(const uint2*)(myPre + r*528 + l*8);
      const uint2 gB = *(const uint2*)(myPre + (8+r)*528 + l*8);
      float cnA, p1A, cnB, p1B;
      CELL(gA, hA, cA, cnA, p1A);
      CELL(gB, hB, cB, cnB, p1B);
      cA = lvA*cnA; cB = cnB;
      p1A *= lvA;
      float vx = p1A, vy = p1B;
#pragma unroll
      for (int off = 32; off; off >>= 1) { vx += __shfl_xor(vx, off); vy += __shfl_xor(vy, off); }
      if (l == 0) slot[buf*16 + w] = make_float2(vx, vy);
      __syncthreads();
      const float4* pp = (const float4*)(slot + buf*16);
      float sA = 0.f, sB = 0.f;
#pragma unroll
      for (int w2 = 0; w2 < 8; ++w2) { const float4 q = pp[w2]; sA += q.x + q.z; sB += q.y + q.w; }
      hA = sA; hB = sB;
      buf ^= 1;
    }
  }

  // ---- main: 8 windows x 4 step-pairs; cell2 batched per window ----
  for (int m = 0; m < 8; ++m) {
    {
      const int rm = r16 & 3, sel = r16 >> 2;
      const unsigned short* rp =
          (sel == 0) ? (xst + (16 + 4*m + rm)*16)
        : (sel == 1) ? (fst + (4*m + rm)*16)
        : (sel == 2) ? (xst + (48 + 4*m + rm)*16)
        :              (fst + (32 + 4*m + rm)*16);
      stage_window(rp);
    }
    float hhA[4], hhB[4], chA[4], chB[4];
#pragma unroll
    for (int r = 0; r < 4; ++r) {
      const uint2 gA = *(const uint2*)(myPre + r*528 + l*8);
      const uint2 gB = *(const uint2*)(myPre + (8+r)*528 + l*8);
      float cnA, p1A, cnB, p1B;
      CELL(gA, hA, cA, cnA, p1A);
      CELL(gB, hB, cB, cnB, p1B);
      cA = cnA; cB = cnB; chA[r] = cnA; chB[r] = cnB;
      float vx = p1A, vy = p1B;
#pragma unroll
      for (int off = 32; off; off >>= 1) { vx += __shfl_xor(vx, off); vy += __shfl_xor(vy, off); }
      if (l == 0) slot[buf*16 + w] = make_float2(vx, vy);
      __syncthreads();
      if (r == 0 && m > 0 && j < 8) {      // publish previous window's fprog
        const float2* pq = p2f + ((m-1) & 1)*64;
        const int rr2 = j & 3; const bool isB = j >= 4;
        float s = 0.f;
#pragma unroll
        for (int w2 = 0; w2 < 16; ++w2) { const float2 q = pq[w2*4 + rr2]; s += isB ? q.y : q.x; }
        out[S_TOT + (isB ? tB : tA) + 4*(m-1) + rr2] = s;
      }
      const float4* pp = (const float4*)(slot + buf*16);
      float sA = 0.f, sB = 0.f;
#pragma unroll
      for (int w2 = 0; w2 < 8; ++w2) { const float4 q = pp[w2]; sA += q.x + q.z; sB += q.y + q.w; }
      hA = sA; hB = sB; hhA[r] = sA; hhB[r] = sB;
      if (j == 0) { out[tA + 4*m + r] = sA; out[tB + 4*m + r] = sB; }
      buf ^= 1;
    }
    // cell2 batch: 4 pairs, independent, using post-cell1 (h,c) history
    float p2A[4], p2B[4];
#pragma unroll
    for (int r = 0; r < 4; ++r) {
      const uint2 gA2 = *(const uint2*)(myPre + (4+r)*528 + l*8);
      const uint2 gB2 = *(const uint2*)(myPre + (12+r)*528 + l*8);
      float d1, d2;
      CELL(gA2, hhA[r], chA[r], d1, p2A[r]);
      CELL(gB2, hhB[r], chB[r], d2, p2B[r]);
    }
#pragma unroll
    for (int r = 0; r < 4; ++r) {
#pragma unroll
      for (int off = 32; off; off >>= 1) {
        p2A[r] += __shfl_xor(p2A[r], off);
        p2B[r] += __shfl_xor(p2B[r], off);
      }
    }
    if (l == 0) {
#pragma unroll
      for (int r = 0; r < 4; ++r) p2f[(m & 1)*64 + w*4 + r] = make_float2(p2A[r], p2B[r]);
    }
  }
  __syncthreads();
  if (j < 8) {
    const float2* pq = p2f + (7 & 1)*64;
    const int rr2 = j & 3; const bool isB = j >= 4;
    float s = 0.f;
#pragma unroll
    for (int w2 = 0; w2 < 16; ++w2) { const float2 q = pq[w2*4 + rr2]; s += isB ? q.y : q.x; }
    out[S_TOT + (isB ? tB : tA) + 28 + rr2] = s;
  }
}

extern "C" void kernel_launch(void* const* d_in, const int* in_sizes, int n_in,
                              void* d_out, int out_size, void* d_ws, size_t ws_size,
                              hipStream_t stream) {
  const float* x    = (const float*)d_in[0];
  const float* W_ih = (const float*)d_in[1];
  const float* W_hh = (const float*)d_in[2];
  const float* b_ih = (const float*)d_in[3];
  const float* b_hh = (const float*)d_in[4];
  const float* W_hr = (const float*)d_in[5];
  const float* Wf1  = (const float*)d_in[6];
  const float* bf1  = (const float*)d_in[7];
  const float* Wf2  = (const float*)d_in[8];
  const float* bf2  = (const float*)d_in[9];
  float* out = (float*)d_out;
  unsigned short* wsW = (unsigned short*)d_ws;
  float* ws2 = (float*)((char*)d_ws + 131072);

  hipLaunchKernelGGL(prep_k, dim3(47), dim3(256), 0, stream,
                     W_ih, b_ih, b_hh, Wf1, bf1, Wf2, bf2, wsW, ws2);
  (void)hipFuncSetAttribute((const void*)lstm_scan_k,
                            hipFuncAttributeMaxDynamicSharedMemorySize, SMEM_TOT);
  hipLaunchKernelGGL(lstm_scan_k, dim3(256), dim3(1024), SMEM_TOT, stream,
                     x, W_hh, W_hr, wsW, ws2, out);
}